// Round 17
// baseline (60.759 us; speedup 1.0000x reference)
//
#include <hip/hip_runtime.h>
#include <math.h>

#define CTXN 336
#define PREDN 30
#define NSAMP 100
#define BATCH 1024
#define TPAST 512
#define HID 128
#define NTF 4
#define SFK 4826          /* th(2) + 14*336 + 120 : maps to W1 rows 30..4855 */
#define SFKP 4832         /* padded to multiple of 32; pad region zeroed */
#define KC 4
#define KCH 1216          /* 3 chunks of 1216 + last 1184; all %32==0 */

/* ---- ws layout in BYTES ---- */
#define SFB_OFF    0u                        /* ush  [1024][4832]   9,895,936 */
#define W1T_OFF    9895936u                  /* ush  [128][4832]    1,236,992 */
#define LS_OFF_B   11132928u                 /* f32  loc[1024], scale[1024]   */
#define ZF_OFF     11141120u                 /* f32  [100][1024][32] 13,107,200 */
#define PART_OFF_B 30801920u                 /* f32  [4][1024][128]  2,097,152 */
#define WPK_OFF_B  39714816u                 /* ush  24576 packs (49152 B)    */

/* K1 grid: feat FIRST (longest blocks), then w1t, wpk */
#define NB_FEAT 1024
#define NB_W1T  151
#define NB_WPK  16
#define NB_PREP (NB_FEAT+NB_W1T+NB_WPK)

/* K2 grid: base (256, longest) first, then zgen (3200) */
#define NB_BASE 256
#define NB_ZGEN 3200
#define NB_BZ   (NB_BASE+NB_ZGEN)

typedef unsigned short ush;
typedef __attribute__((ext_vector_type(8))) short bf16x8;
typedef __attribute__((ext_vector_type(4))) float f32x4;

__device__ inline unsigned rotl32(unsigned x, unsigned d){ return (x<<d)|(x>>(32u-d)); }

/* XLA ErfInv32 (Giles); log1p via hw v_log on (1-x)(1+x), hw sqrt */
__device__ inline float erfinv_f32(float x){
  float t1 = (1.0f - x)*(1.0f + x);
  float w = -0.69314718056f * __builtin_amdgcn_logf(t1);
  float p;
  if (w < 5.0f) {
    w -= 2.5f;
    p = 2.81022636e-08f;
    p = fmaf(p, w, 3.43273939e-07f);
    p = fmaf(p, w, -3.5233877e-06f);
    p = fmaf(p, w, -4.39150654e-06f);
    p = fmaf(p, w, 0.00021858087f);
    p = fmaf(p, w, -0.00125372503f);
    p = fmaf(p, w, -0.00417768164f);
    p = fmaf(p, w, 0.246640727f);
    p = fmaf(p, w, 1.50140941f);
  } else {
    w = __builtin_amdgcn_sqrtf(w) - 3.0f;
    p = -0.000200214257f;
    p = fmaf(p, w, 0.000100950558f);
    p = fmaf(p, w, 0.00134934322f);
    p = fmaf(p, w, -0.00367342844f);
    p = fmaf(p, w, 0.00573950773f);
    p = fmaf(p, w, -0.0076224613f);
    p = fmaf(p, w, 0.00943887047f);
    p = fmaf(p, w, 1.00167406f);
    p = fmaf(p, w, 2.83297682f);
  }
  return p*x;
}

/* gelu(tanh form): 8 VALU via hw exp2/rcp */
__device__ inline float gelu_tanh(float x){
  float x2 = x*x;
  float q  = fmaf(0.044715f*x2, x, x);
  float e  = __builtin_amdgcn_exp2f(2.302114202f * q);
  float r  = __builtin_amdgcn_rcpf(e + 1.0f);
  return fmaf(-x, r, x);
}

/* f32 -> bf16 RNE */
__device__ inline ush f2bf(float f){
  unsigned u = __float_as_uint(f);
  unsigned r = (u + 0x7FFFu + ((u>>16)&1u)) >> 16;
  return (ush)r;
}

/* order-preserving float<->uint map (total order; exact) */
__device__ inline unsigned ordf(float f){
  unsigned u = __float_as_uint(f);
  return (u & 0x80000000u) ? ~u : (u | 0x80000000u);
}
__device__ inline float unordf(unsigned ou){
  unsigned u = (ou & 0x80000000u) ? (ou & 0x7FFFFFFFu) : ~ou;
  return __uint_as_float(u);
}

__device__ inline float blockReduceSum256(float v, volatile float* red){
  for (int o=32;o>0;o>>=1) v += __shfl_down(v, o, 64);
  int w = threadIdx.x>>6, lane = threadIdx.x&63;
  __syncthreads();
  if (lane==0) red[w]=v;
  __syncthreads();
  return red[0]+red[1]+red[2]+red[3];
}

__device__ inline unsigned blockReduceMin256(unsigned v, volatile unsigned* redu){
  for (int o=32;o>0;o>>=1){ unsigned t = __shfl_down(v, o, 64); v = (t<v)?t:v; }
  int w = threadIdx.x>>6, lane = threadIdx.x&63;
  __syncthreads();
  if (lane==0) redu[w]=v;
  __syncthreads();
  unsigned a = redu[0], b = redu[1], c = redu[2], d = redu[3];
  unsigned ab = (a<b)?a:b, cd = (c<d)?c:d;
  return (ab<cd)?ab:cd;
}

/* 4-wide ILP threefry rounds */
__device__ inline void tf_rounds4(unsigned (&x0)[4], unsigned (&x1)[4],
                                  int r0, int r1, int r2, int r3){
  #pragma unroll
  for (int i=0;i<4;i++){ x0[i]+=x1[i]; x1[i]=rotl32(x1[i],r0); x1[i]^=x0[i]; }
  #pragma unroll
  for (int i=0;i<4;i++){ x0[i]+=x1[i]; x1[i]=rotl32(x1[i],r1); x1[i]^=x0[i]; }
  #pragma unroll
  for (int i=0;i<4;i++){ x0[i]+=x1[i]; x1[i]=rotl32(x1[i],r2); x1[i]^=x0[i]; }
  #pragma unroll
  for (int i=0;i<4;i++){ x0[i]+=x1[i]; x1[i]=rotl32(x1[i],r3); x1[i]^=x0[i]; }
}

/* ============ K1 prep: feat | W1 transpose | small packs ============ */
__global__ __launch_bounds__(256) void prep_kernel(
    const float* __restrict__ pt, const float* __restrict__ ptf,
    const float* __restrict__ ftf, const float* __restrict__ W1,
    const float* __restrict__ W2, const float* __restrict__ W3,
    char* __restrict__ wsb)
{
  __shared__ float seg[343];
  __shared__ __attribute__((aligned(16))) float segA[CTXN];
  __shared__ float dbuf[CTXN];
  __shared__ float rbuf[CTXN];
  __shared__ float red[4];
  __shared__ unsigned redu[4];
  __shared__ int bins[16];
  const int bid = blockIdx.x;
  const int tid = threadIdx.x;

  if (bid >= NB_FEAT){
    const int b2id = bid - NB_FEAT;
    if (b2id < NB_W1T){                     /* ---- W1[30:] -> col-major bf16 ---- */
      ush* w1t = (ush*)(wsb + W1T_OFF);
      const int k0 = b2id*32;
      const int col = tid >> 1;
      const int kh  = (tid & 1)*16;
      ush v[16];
      #pragma unroll
      for (int j=0;j<16;j++){
        int k = k0 + kh + j;
        v[j] = (k < SFK) ? f2bf(W1[(size_t)(30+k)*HID + col]) : (ush)0;
      }
      ush* dst = w1t + (size_t)col*SFKP + k0 + kh;
      *(uint4*)dst       = *(const uint4*)&v[0];
      *(uint4*)(dst + 8) = *(const uint4*)&v[8];
      return;
    }
    {                                       /* ---- small packs (w1z/w2/w3) ---- */
      ush* wb = (ush*)(wsb + WPK_OFF_B);
      int t2 = (b2id - NB_W1T)*256 + tid;
      { int col = t2>>5, k = t2&31;
        wb[t2] = (k<30) ? f2bf(W1[(size_t)k*HID + col]) : (ush)0; }
      #pragma unroll
      for (int j=0;j<4;j++){
        int i = j*4096 + t2;
        int col = i>>7, k = i&127;
        wb[4096 + i] = f2bf(W2[(size_t)k*HID + col]);
      }
      { int col = t2>>7, k = t2&127;
        wb[20480 + t2] = (col<30) ? f2bf(W3[(size_t)k*PREDN + col]) : (ush)0; }
      return;
    }
  }

  /* ---- features (bid 0..1023, longest-first) ---- */
  const int b = bid;
  for (int i = tid; i < 343; i += 256) seg[i] = pt[(size_t)b*TPAST + 169 + i];
  __syncthreads();
  for (int i = tid; i < CTXN; i += 256) segA[i] = seg[7+i];
  __syncthreads();

  /* -------- median via exact radix-select (orderable-uint nibbles) -------- */
  const unsigned oe0 = ordf(segA[tid]);
  const bool has1 = (tid < CTXN - 256);
  const unsigned oe1 = has1 ? ordf(segA[256 + tid]) : 0u;

  unsigned pfx = 0u; int kk = 167;          /* find 167th smallest (0-indexed) */
  #pragma unroll
  for (int shift = 28; shift >= 0; shift -= 4){
    __syncthreads();
    if (tid < 16) bins[tid] = 0;
    __syncthreads();
    const unsigned hi_mask = (shift==28) ? 0u : (0xFFFFFFFFu << (shift+4));
    if (((oe0 ^ pfx) & hi_mask) == 0) atomicAdd(&bins[(oe0>>shift)&15], 1);
    if (has1 && (((oe1 ^ pfx) & hi_mask) == 0)) atomicAdd(&bins[(oe1>>shift)&15], 1);
    __syncthreads();
    int cum = 0, sel = 15;                  /* all threads scan redundantly */
    #pragma unroll
    for (int bb = 0; bb < 16; bb++){
      int c = bins[bb];
      if (kk < cum + c){ sel = bb; break; }
      cum += c;
    }
    kk -= cum;
    pfx |= ((unsigned)sel) << shift;
  }
  const float v167 = unordf(pfx);

  /* rank 168: duplicates -> same; else min over { x > v167 } */
  float cle = ((oe0 <= pfx) ? 1.f : 0.f) + ((has1 && oe1 <= pfx) ? 1.f : 0.f);
  cle = blockReduceSum256(cle, red);
  unsigned mg = (oe0 > pfx) ? oe0 : 0xFFFFFFFFu;
  if (has1 && oe1 > pfx && oe1 < mg) mg = oe1;
  mg = blockReduceMin256(mg, redu);
  const float v168 = (cle >= 168.5f) ? v167 : unordf(mg);
  const float loc = 0.5f*(v167 + v168);

  float part = 0.f;
  for (int t=tid;t<CTXN;t+=256) part += fabsf(segA[t]-loc);
  part = blockReduceSum256(part, red);
  float scale = fmaxf(part/(float)CTXN, 1e-6f);

  float pd = 0.f;
  for (int t=tid;t<CTXN;t+=256){
    float d = (t==0)?0.f:(seg[7+t]-seg[6+t]);
    dbuf[t]=d; pd += fabsf(d);
  }
  pd = blockReduceSum256(pd, red);
  float dden = fmaxf(pd/(float)CTXN, 1e-6f);

  float pr = 0.f;
  for (int t=tid;t<CTXN;t+=256){
    int a = t-4; if (a<0) a=0;
    int n = t+1-a;
    float s=0.f, s2s=0.f;
    for (int jj=a;jj<=t;jj++){ float v=seg[7+jj]; s+=v; s2s+=v*v; }
    float fn = (float)n;
    float var = (s2s - s*s/fn) / fmaxf(fn-1.f, 1.f);
    float r = (t>=2)? sqrtf(fmaxf(var,1e-12f)) : 0.f;
    rbuf[t]=r; pr += r;
  }
  pr = blockReduceSum256(pr, red);
  float rden = fmaxf(pr/(float)CTXN, 1e-6f);
  __syncthreads();

  ush* sf = (ush*)(wsb + SFB_OFF) + (size_t)b*SFKP;
  float* ls = (float*)(wsb + LS_OFF_B);
  if (tid<2) sf[tid] = (ush)0x3F80;
  if (tid<SFKP-SFK) sf[SFK+tid] = 0;
  float iscale = 1.0f/scale, iden = 1.0f/dden, irden = 1.0f/rden;
  for (int t=tid;t<CTXN;t+=256){
    #pragma unroll
    for (int c=0;c<8;c++)
      sf[2 + c*CTXN + t] = f2bf((seg[7 - c + t] - loc)*iscale);
    sf[2+8*CTXN+t] = f2bf(dbuf[t]*iden);
    sf[2+9*CTXN+t] = f2bf(rbuf[t]*irden);
    float4 tf4 = *(const float4*)(ptf + (size_t)b*TPAST*NTF + (size_t)(176+t)*NTF);
    sf[2 + 10*CTXN + t] = f2bf(tf4.x);
    sf[2 + 11*CTXN + t] = f2bf(tf4.y);
    sf[2 + 12*CTXN + t] = f2bf(tf4.z);
    sf[2 + 13*CTXN + t] = f2bf(tf4.w);
  }
  for (int i=tid;i<NTF*PREDN;i+=256){
    int f = i/PREDN, t = i - f*PREDN;
    sf[2+14*CTXN + i] = f2bf(ftf[(size_t)b*PREDN*NTF + t*NTF + f]);
  }
  if (tid==0){ ls[b] = loc; ls[BATCH + b] = scale; }
}

/* ============ K2: base split-K GEMM (MFMA) || zgen (VALU) — pipe overlap ===== */
__global__ __launch_bounds__(256) void bz_kernel(
    const char* __restrict__ wsb, float* __restrict__ partb)
{
  const int bid = blockIdx.x;
  const int tid = threadIdx.x;

  if (bid < NB_BASE){                       /* ---- base_partial (MFMA) ---- */
    const ush* sfb = (const ush*)(wsb + SFB_OFF);
    const ush* w1t = (const ush*)(wsb + W1T_OFF);
    const int w = tid>>6, l = tid&63;
    const int li = l&15, lk = l>>4;
    const int rb = (bid & 63)*16;
    const int kc = bid >> 6;
    const int kbeg = kc*KCH;
    const int kend = min(SFKP, kbeg+KCH);

    f32x4 acc0 = {0.f,0.f,0.f,0.f}, acc1 = {0.f,0.f,0.f,0.f};
    const ush* ap  = sfb + (size_t)(rb + li)*SFKP + lk*8;
    const ush* b0p = w1t + (size_t)(w*32 + li)*SFKP + lk*8;
    const ush* b1p = b0p + (size_t)16*SFKP;

    #pragma unroll 4
    for (int kk0 = kbeg; kk0 < kend; kk0 += 32){
      bf16x8 a  = *(const bf16x8*)(ap  + kk0);
      bf16x8 b0 = *(const bf16x8*)(b0p + kk0);
      bf16x8 b1 = *(const bf16x8*)(b1p + kk0);
      acc0 = __builtin_amdgcn_mfma_f32_16x16x32_bf16(a, b0, acc0, 0, 0, 0);
      acc1 = __builtin_amdgcn_mfma_f32_16x16x32_bf16(a, b1, acc1, 0, 0, 0);
    }
    float* p = partb + ((size_t)kc*BATCH + rb)*HID;
    #pragma unroll
    for (int q=0;q<4;q++){
      p[(lk*4+q)*HID + w*32      + li] = acc0[q];
      p[(lk*4+q)*HID + w*32 + 16 + li] = acc1[q];
    }
    return;
  }

  /* ---- zgen: ILP-4 threefry (VALU; overlaps base's MFMA on same CUs) ---- */
  {
    float* zf = (float*)(wsb + ZF_OFF);
    const int g  = (bid - NB_BASE)*256 + tid;
    const int sb = g >> 3;
    const int t0 = (g & 7) * 4;
    const int s = sb >> 10, b = sb & 1023;
    const unsigned jb = (unsigned)(s*30720 + b*30 + t0);

    const unsigned k0=0u, k1=42u, k2 = k0^k1^0x1BD11BDAu;
    unsigned x0[4], x1[4];
    #pragma unroll
    for (int i=0;i<4;i++){ x0[i] = k0; x1[i] = (jb + (unsigned)i) + k1; }

    tf_rounds4(x0,x1,13,15,26,6);
    #pragma unroll
    for (int i=0;i<4;i++){ x0[i]+=k1; x1[i]+=k2+1u; }
    tf_rounds4(x0,x1,17,29,16,24);
    #pragma unroll
    for (int i=0;i<4;i++){ x0[i]+=k2; x1[i]+=k0+2u; }
    tf_rounds4(x0,x1,13,15,26,6);
    #pragma unroll
    for (int i=0;i<4;i++){ x0[i]+=k0; x1[i]+=k1+3u; }
    tf_rounds4(x0,x1,17,29,16,24);
    #pragma unroll
    for (int i=0;i<4;i++){ x0[i]+=k1; x1[i]+=k2+4u; }
    tf_rounds4(x0,x1,13,15,26,6);
    #pragma unroll
    for (int i=0;i<4;i++){ x0[i]+=k2; x1[i]+=k0+5u; }

    const float LO = -0.99999994f;
    float vout[4];
    #pragma unroll
    for (int i=0;i<4;i++){
      unsigned bits = x0[i]^x1[i];
      float f = __uint_as_float((bits>>9)|0x3f800000u) - 1.0f;
      float u = fmaxf(LO, f*2.0f + LO);
      vout[i] = 1.41421356f * erfinv_f32(u);
    }
    float4 v; v.x=vout[0]; v.y=vout[1]; v.z=vout[2]; v.w=vout[3];
    *(float4*)(zf + (size_t)sb*32 + t0) = v;
  }
}

/* ============ K3 mlp: grid (64,8)=512 blocks = 2/CU; u<4, s = sg+8*(wv+4u);
   W2 fragments hoisted to REGISTERS once per block (128 VGPR, reused by all
   4 units) — cuts per-unit LDS reads 48->16; launch_bounds(256,2). ========= */
__global__ __launch_bounds__(256, 2) void mlp_kernel(
    const char* __restrict__ wsb, const float* __restrict__ b1v,
    const float* __restrict__ b2v, const float* __restrict__ b3v,
    float* __restrict__ out)
{
  const int tid = threadIdx.x;
  const int wv = tid>>6, l = tid&63;
  const int li = l&15, lk = l>>4;
  const int r0 = blockIdx.x*16;
  const int sg = blockIdx.y;               /* 0..7 */

  const float* ls    = (const float*)(wsb + LS_OFF_B);
  const float* zf    = (const float*)(wsb + ZF_OFF);
  const float* partb = (const float*)(wsb + PART_OFF_B);
  const char*  wpkc  = wsb + WPK_OFF_B;

  __shared__ __attribute__((aligned(16))) ush  wlds[24576];  /* 48KB swizzled weights */
  __shared__ __attribute__((aligned(16))) float blds[2048];  /* 8KB base rows (reduced) */
  __shared__ __attribute__((aligned(16))) ush  hb4[4][2048]; /* wave-private h buf */
  char* hb = (char*)hb4[wv];
  char* wl = (char*)wlds;

  /* ---- stage weights (swizzle at write; linear global read) ---- */
  #pragma unroll
  for (int i=0;i<12;i++){
    int byte = (i*256 + tid)*16;
    int swz;
    if (byte < 8192){ int col = byte>>6; swz = byte ^ ((col&3)<<4); }
    else if (byte < 40960){ int X = byte - 8192; int col = X>>8; swz = 8192 + (X ^ ((col&7)<<4)); }
    else { int X = byte - 40960; int col = X>>8; swz = 40960 + (X ^ ((col&7)<<4)); }
    *(float4*)(wl + swz) = *(const float4*)(wpkc + byte);
  }
  /* ---- stage base rows with fused split-K reduce: blds = b1 + sum partb ---- */
  #pragma unroll
  for (int k=0;k<8;k++){
    int i = k*256 + tid;               /* 0..2047 = row*128 + h */
    float acc = b1v[i & 127];
    #pragma unroll
    for (int kc=0;kc<KC;kc++)
      acc += partb[(size_t)kc*BATCH*HID + (size_t)r0*HID + i];
    blds[i] = acc;
  }
  __syncthreads();

  /* ---- block-invariant registers ---- */
  const int swzli  = (li&7)<<4;
  const int swzli3 = (li&3)<<4;

  /* W2 fragments: identical for all 4 units -> hoist to registers (128 VGPR) */
  bf16x8 w2f[8][4];
  #pragma unroll
  for (int ct=0; ct<8; ct++)
    #pragma unroll
    for (int ks=0; ks<4; ks++)
      w2f[ct][ks] = *(const bf16x8*)(wl + 8192 + (((ct*16+li)*256 + ks*64 + lk*16) ^ swzli));

  float b2r[8];
  #pragma unroll
  for (int ct=0; ct<8; ct++) b2r[ct] = b2v[ct*16 + li];
  float b3r[2];
  #pragma unroll
  for (int ct3=0; ct3<2; ct3++){
    int col = ct3*16 + li;
    b3r[ct3] = (col < PREDN) ? b3v[col] : 0.f;
  }
  float loc4[4], scl4[4];
  #pragma unroll
  for (int q=0;q<4;q++){
    int gb = r0 + lk*4 + q;
    loc4[q] = ls[gb];
    scl4[q] = ls[BATCH + gb];
  }

  #pragma unroll
  for (int u=0; u<4; u++){
    const int s = sg + 8*(wv + 4*u);   /* wave-uniform, DISTINCT per wave */
    if (s >= NSAMP) continue;

    /* early global loads: z A-frag source + epilogue z */
    const float* zrow = zf + ((size_t)(s*BATCH + r0 + li))*32 + lk*8;
    float4 za0 = *(const float4*)zrow;
    float4 za1 = *(const float4*)(zrow + 4);
    float zep[2][4];
    #pragma unroll
    for (int q=0;q<4;q++){
      const float* zr2 = zf + ((size_t)(s*BATCH + r0 + lk*4 + q))*32;
      zep[0][q] = zr2[li];
      zep[1][q] = zr2[16 + li];
    }

    /* acc init from base (LDS) */
    f32x4 acc[8];
    #pragma unroll
    for (int ct=0; ct<8; ct++){
      #pragma unroll
      for (int q=0;q<4;q++)
        acc[ct][q] = blds[(lk*4+q)*HID + ct*16 + li];
    }

    bf16x8 az;
    az[0]=(short)f2bf(za0.x); az[1]=(short)f2bf(za0.y);
    az[2]=(short)f2bf(za0.z); az[3]=(short)f2bf(za0.w);
    az[4]=(short)f2bf(za1.x); az[5]=(short)f2bf(za1.y);
    az[6]=(short)f2bf(za1.z); az[7]=(short)f2bf(za1.w);

    /* W1z stage (LDS swizzled reads) */
    #pragma unroll
    for (int ct=0; ct<8; ct++){
      bf16x8 w1f = *(const bf16x8*)(wl + (((ct*16+li)*64 + lk*16) ^ swzli3));
      acc[ct] = __builtin_amdgcn_mfma_f32_16x16x32_bf16(az, w1f, acc[ct], 0, 0, 0);
    }
    #pragma unroll
    for (int ct=0; ct<8; ct++){
      int col2 = (ct*16 + li)*2;
      #pragma unroll
      for (int q=0;q<4;q++){
        int r = lk*4 + q;
        *(ush*)(hb + r*256 + (col2 ^ ((r&7)<<4))) = f2bf(gelu_tanh(acc[ct][q]));
      }
    }

    /* W2 stage: K=128, B-frags from registers */
    f32x4 acc2[8];
    #pragma unroll
    for (int ct=0; ct<8; ct++){
      acc2[ct][0]=b2r[ct]; acc2[ct][1]=b2r[ct]; acc2[ct][2]=b2r[ct]; acc2[ct][3]=b2r[ct];
    }
    #pragma unroll
    for (int ks=0; ks<4; ks++){
      bf16x8 a2 = *(const bf16x8*)(hb + li*256 + ((ks*64 + lk*16) ^ swzli));
      #pragma unroll
      for (int ct=0; ct<8; ct++)
        acc2[ct] = __builtin_amdgcn_mfma_f32_16x16x32_bf16(a2, w2f[ct][ks], acc2[ct], 0, 0, 0);
    }
    #pragma unroll
    for (int ct=0; ct<8; ct++){
      int col2 = (ct*16 + li)*2;
      #pragma unroll
      for (int q=0;q<4;q++){
        int r = lk*4 + q;
        *(ush*)(hb + r*256 + (col2 ^ ((r&7)<<4))) = f2bf(gelu_tanh(acc2[ct][q]));
      }
    }

    /* W3 stage */
    f32x4 acc3[2];
    #pragma unroll
    for (int ct3=0; ct3<2; ct3++){
      acc3[ct3][0]=b3r[ct3]; acc3[ct3][1]=b3r[ct3];
      acc3[ct3][2]=b3r[ct3]; acc3[ct3][3]=b3r[ct3];
    }
    #pragma unroll
    for (int ks=0; ks<4; ks++){
      bf16x8 a3 = *(const bf16x8*)(hb + li*256 + ((ks*64 + lk*16) ^ swzli));
      #pragma unroll
      for (int ct3=0; ct3<2; ct3++){
        bf16x8 w3f = *(const bf16x8*)(wl + 40960 + (((ct3*16+li)*256 + ks*64 + lk*16) ^ swzli));
        acc3[ct3] = __builtin_amdgcn_mfma_f32_16x16x32_bf16(a3, w3f, acc3[ct3], 0, 0, 0);
      }
    }

    /* epilogue: (z - u)*scale + loc */
    #pragma unroll
    for (int ct3=0; ct3<2; ct3++){
      int col3 = ct3*16 + li;
      if (col3 < PREDN){
        #pragma unroll
        for (int q=0;q<4;q++){
          int gb = r0 + lk*4 + q;
          out[(size_t)gb*(NSAMP*PREDN) + s*PREDN + col3] =
              (zep[ct3][q] - acc3[ct3][q])*scl4[q] + loc4[q];
        }
      }
    }
  }
}

extern "C" void kernel_launch(void* const* d_in, const int* in_sizes, int n_in,
                              void* d_out, int out_size, void* d_ws, size_t ws_size,
                              hipStream_t stream) {
  (void)in_sizes; (void)n_in; (void)out_size; (void)ws_size;
  const float* pt  = (const float*)d_in[0];
  const float* ptf = (const float*)d_in[2];
  const float* ftf = (const float*)d_in[3];
  const float* W1  = (const float*)d_in[4];
  const float* b1  = (const float*)d_in[5];
  const float* W2  = (const float*)d_in[6];
  const float* b2  = (const float*)d_in[7];
  const float* W3  = (const float*)d_in[8];
  const float* b3  = (const float*)d_in[9];
  float* out = (float*)d_out;
  char* wsb  = (char*)d_ws;

  hipLaunchKernelGGL(prep_kernel, dim3(NB_PREP), dim3(256), 0, stream,
                     pt, ptf, ftf, W1, W2, W3, wsb);
  hipLaunchKernelGGL(bz_kernel, dim3(NB_BZ), dim3(256), 0, stream,
                     wsb, (float*)(wsb + PART_OFF_B));
  hipLaunchKernelGGL(mlp_kernel, dim3(64, 8), dim3(256), 0, stream,
                     wsb, b1, b2, b3, out);
}

// Round 18
// 52.976 us; speedup vs baseline: 1.1469x; 1.1469x over previous
//
#include <hip/hip_runtime.h>
#include <math.h>

#define CTXN 336
#define PREDN 30
#define NSAMP 100
#define BATCH 1024
#define TPAST 512
#define HID 128
#define NTF 4
#define SFK 4826          /* th(2) + 14*336 + 120 : maps to W1 rows 30..4855 */
#define SFKP 4832         /* padded to multiple of 32; pad region zeroed */
#define KC 8
#define KCH 608           /* 7 chunks of 608 + last 576; all %32==0 */

/* ---- ws layout in BYTES ---- */
#define SFB_OFF    0u                        /* ush  [1024][4832]   9,895,936 */
#define W1T_OFF    9895936u                  /* ush  [128][4832]    1,236,992 */
#define LS_OFF_B   11132928u                 /* f32  loc[1024], scale[1024]   */
#define ZF_OFF     11141120u                 /* f32  [100][1024][32] 13,107,200 */
#define PART_OFF_B 30801920u                 /* f32  [8][1024][128]  4,194,304 */
#define WPK_OFF_B  39714816u                 /* ush  24576 packs (49152 B)    */

/* K1 grid: feat FIRST (longest blocks), then w1t, wpk */
#define NB_FEAT 1024
#define NB_W1T  151
#define NB_WPK  16
#define NB_PREP (NB_FEAT+NB_W1T+NB_WPK)

/* K2 grid: base (512 = 2/CU, longest) first, then zgen (3200) */
#define NB_BASE 512
#define NB_ZGEN 3200
#define NB_BZ   (NB_BASE+NB_ZGEN)

typedef unsigned short ush;
typedef __attribute__((ext_vector_type(8))) short bf16x8;
typedef __attribute__((ext_vector_type(4))) float f32x4;

__device__ inline unsigned rotl32(unsigned x, unsigned d){ return (x<<d)|(x>>(32u-d)); }

/* XLA ErfInv32 (Giles); log1p via hw v_log on (1-x)(1+x), hw sqrt */
__device__ inline float erfinv_f32(float x){
  float t1 = (1.0f - x)*(1.0f + x);
  float w = -0.69314718056f * __builtin_amdgcn_logf(t1);
  float p;
  if (w < 5.0f) {
    w -= 2.5f;
    p = 2.81022636e-08f;
    p = fmaf(p, w, 3.43273939e-07f);
    p = fmaf(p, w, -3.5233877e-06f);
    p = fmaf(p, w, -4.39150654e-06f);
    p = fmaf(p, w, 0.00021858087f);
    p = fmaf(p, w, -0.00125372503f);
    p = fmaf(p, w, -0.00417768164f);
    p = fmaf(p, w, 0.246640727f);
    p = fmaf(p, w, 1.50140941f);
  } else {
    w = __builtin_amdgcn_sqrtf(w) - 3.0f;
    p = -0.000200214257f;
    p = fmaf(p, w, 0.000100950558f);
    p = fmaf(p, w, 0.00134934322f);
    p = fmaf(p, w, -0.00367342844f);
    p = fmaf(p, w, 0.00573950773f);
    p = fmaf(p, w, -0.0076224613f);
    p = fmaf(p, w, 0.00943887047f);
    p = fmaf(p, w, 1.00167406f);
    p = fmaf(p, w, 2.83297682f);
  }
  return p*x;
}

/* gelu(tanh form): 8 VALU via hw exp2/rcp */
__device__ inline float gelu_tanh(float x){
  float x2 = x*x;
  float q  = fmaf(0.044715f*x2, x, x);
  float e  = __builtin_amdgcn_exp2f(2.302114202f * q);
  float r  = __builtin_amdgcn_rcpf(e + 1.0f);
  return fmaf(-x, r, x);
}

/* f32 -> bf16 RNE */
__device__ inline ush f2bf(float f){
  unsigned u = __float_as_uint(f);
  unsigned r = (u + 0x7FFFu + ((u>>16)&1u)) >> 16;
  return (ush)r;
}

/* order-preserving float<->uint map (total order; exact) */
__device__ inline unsigned ordf(float f){
  unsigned u = __float_as_uint(f);
  return (u & 0x80000000u) ? ~u : (u | 0x80000000u);
}
__device__ inline float unordf(unsigned ou){
  unsigned u = (ou & 0x80000000u) ? (ou & 0x7FFFFFFFu) : ~ou;
  return __uint_as_float(u);
}

__device__ inline float blockReduceSum256(float v, volatile float* red){
  for (int o=32;o>0;o>>=1) v += __shfl_down(v, o, 64);
  int w = threadIdx.x>>6, lane = threadIdx.x&63;
  __syncthreads();
  if (lane==0) red[w]=v;
  __syncthreads();
  return red[0]+red[1]+red[2]+red[3];
}

__device__ inline unsigned blockReduceMin256(unsigned v, volatile unsigned* redu){
  for (int o=32;o>0;o>>=1){ unsigned t = __shfl_down(v, o, 64); v = (t<v)?t:v; }
  int w = threadIdx.x>>6, lane = threadIdx.x&63;
  __syncthreads();
  if (lane==0) redu[w]=v;
  __syncthreads();
  unsigned a = redu[0], b = redu[1], c = redu[2], d = redu[3];
  unsigned ab = (a<b)?a:b, cd = (c<d)?c:d;
  return (ab<cd)?ab:cd;
}

/* 4-wide ILP threefry rounds */
__device__ inline void tf_rounds4(unsigned (&x0)[4], unsigned (&x1)[4],
                                  int r0, int r1, int r2, int r3){
  #pragma unroll
  for (int i=0;i<4;i++){ x0[i]+=x1[i]; x1[i]=rotl32(x1[i],r0); x1[i]^=x0[i]; }
  #pragma unroll
  for (int i=0;i<4;i++){ x0[i]+=x1[i]; x1[i]=rotl32(x1[i],r1); x1[i]^=x0[i]; }
  #pragma unroll
  for (int i=0;i<4;i++){ x0[i]+=x1[i]; x1[i]=rotl32(x1[i],r2); x1[i]^=x0[i]; }
  #pragma unroll
  for (int i=0;i<4;i++){ x0[i]+=x1[i]; x1[i]=rotl32(x1[i],r3); x1[i]^=x0[i]; }
}

/* ============ K1 prep: feat | W1 transpose | small packs ============ */
__global__ __launch_bounds__(256) void prep_kernel(
    const float* __restrict__ pt, const float* __restrict__ ptf,
    const float* __restrict__ ftf, const float* __restrict__ W1,
    const float* __restrict__ W2, const float* __restrict__ W3,
    char* __restrict__ wsb)
{
  __shared__ float seg[343];
  __shared__ __attribute__((aligned(16))) float segA[CTXN];
  __shared__ float dbuf[CTXN];
  __shared__ float rbuf[CTXN];
  __shared__ float red[4];
  __shared__ unsigned redu[4];
  __shared__ int bins[16];
  const int bid = blockIdx.x;
  const int tid = threadIdx.x;

  if (bid >= NB_FEAT){
    const int b2id = bid - NB_FEAT;
    if (b2id < NB_W1T){                     /* ---- W1[30:] -> col-major bf16 ---- */
      ush* w1t = (ush*)(wsb + W1T_OFF);
      const int k0 = b2id*32;
      const int col = tid >> 1;
      const int kh  = (tid & 1)*16;
      ush v[16];
      #pragma unroll
      for (int j=0;j<16;j++){
        int k = k0 + kh + j;
        v[j] = (k < SFK) ? f2bf(W1[(size_t)(30+k)*HID + col]) : (ush)0;
      }
      ush* dst = w1t + (size_t)col*SFKP + k0 + kh;
      *(uint4*)dst       = *(const uint4*)&v[0];
      *(uint4*)(dst + 8) = *(const uint4*)&v[8];
      return;
    }
    {                                       /* ---- small packs (w1z/w2/w3) ---- */
      ush* wb = (ush*)(wsb + WPK_OFF_B);
      int t2 = (b2id - NB_W1T)*256 + tid;
      { int col = t2>>5, k = t2&31;
        wb[t2] = (k<30) ? f2bf(W1[(size_t)k*HID + col]) : (ush)0; }
      #pragma unroll
      for (int j=0;j<4;j++){
        int i = j*4096 + t2;
        int col = i>>7, k = i&127;
        wb[4096 + i] = f2bf(W2[(size_t)k*HID + col]);
      }
      { int col = t2>>7, k = t2&127;
        wb[20480 + t2] = (col<30) ? f2bf(W3[(size_t)k*PREDN + col]) : (ush)0; }
      return;
    }
  }

  /* ---- features (bid 0..1023, longest-first) ---- */
  const int b = bid;
  for (int i = tid; i < 343; i += 256) seg[i] = pt[(size_t)b*TPAST + 169 + i];
  __syncthreads();
  for (int i = tid; i < CTXN; i += 256) segA[i] = seg[7+i];
  __syncthreads();

  /* -------- median via exact radix-select (orderable-uint nibbles) -------- */
  const unsigned oe0 = ordf(segA[tid]);
  const bool has1 = (tid < CTXN - 256);
  const unsigned oe1 = has1 ? ordf(segA[256 + tid]) : 0u;

  unsigned pfx = 0u; int kk = 167;          /* find 167th smallest (0-indexed) */
  #pragma unroll
  for (int shift = 28; shift >= 0; shift -= 4){
    __syncthreads();
    if (tid < 16) bins[tid] = 0;
    __syncthreads();
    const unsigned hi_mask = (shift==28) ? 0u : (0xFFFFFFFFu << (shift+4));
    if (((oe0 ^ pfx) & hi_mask) == 0) atomicAdd(&bins[(oe0>>shift)&15], 1);
    if (has1 && (((oe1 ^ pfx) & hi_mask) == 0)) atomicAdd(&bins[(oe1>>shift)&15], 1);
    __syncthreads();
    int cum = 0, sel = 15;                  /* all threads scan redundantly */
    #pragma unroll
    for (int bb = 0; bb < 16; bb++){
      int c = bins[bb];
      if (kk < cum + c){ sel = bb; break; }
      cum += c;
    }
    kk -= cum;
    pfx |= ((unsigned)sel) << shift;
  }
  const float v167 = unordf(pfx);

  /* rank 168: duplicates -> same; else min over { x > v167 } */
  float cle = ((oe0 <= pfx) ? 1.f : 0.f) + ((has1 && oe1 <= pfx) ? 1.f : 0.f);
  cle = blockReduceSum256(cle, red);
  unsigned mg = (oe0 > pfx) ? oe0 : 0xFFFFFFFFu;
  if (has1 && oe1 > pfx && oe1 < mg) mg = oe1;
  mg = blockReduceMin256(mg, redu);
  const float v168 = (cle >= 168.5f) ? v167 : unordf(mg);
  const float loc = 0.5f*(v167 + v168);

  float part = 0.f;
  for (int t=tid;t<CTXN;t+=256) part += fabsf(segA[t]-loc);
  part = blockReduceSum256(part, red);
  float scale = fmaxf(part/(float)CTXN, 1e-6f);

  float pd = 0.f;
  for (int t=tid;t<CTXN;t+=256){
    float d = (t==0)?0.f:(seg[7+t]-seg[6+t]);
    dbuf[t]=d; pd += fabsf(d);
  }
  pd = blockReduceSum256(pd, red);
  float dden = fmaxf(pd/(float)CTXN, 1e-6f);

  float pr = 0.f;
  for (int t=tid;t<CTXN;t+=256){
    int a = t-4; if (a<0) a=0;
    int n = t+1-a;
    float s=0.f, s2s=0.f;
    for (int jj=a;jj<=t;jj++){ float v=seg[7+jj]; s+=v; s2s+=v*v; }
    float fn = (float)n;
    float var = (s2s - s*s/fn) / fmaxf(fn-1.f, 1.f);
    float r = (t>=2)? sqrtf(fmaxf(var,1e-12f)) : 0.f;
    rbuf[t]=r; pr += r;
  }
  pr = blockReduceSum256(pr, red);
  float rden = fmaxf(pr/(float)CTXN, 1e-6f);
  __syncthreads();

  ush* sf = (ush*)(wsb + SFB_OFF) + (size_t)b*SFKP;
  float* ls = (float*)(wsb + LS_OFF_B);
  if (tid<2) sf[tid] = (ush)0x3F80;
  if (tid<SFKP-SFK) sf[SFK+tid] = 0;
  float iscale = 1.0f/scale, iden = 1.0f/dden, irden = 1.0f/rden;
  for (int t=tid;t<CTXN;t+=256){
    #pragma unroll
    for (int c=0;c<8;c++)
      sf[2 + c*CTXN + t] = f2bf((seg[7 - c + t] - loc)*iscale);
    sf[2+8*CTXN+t] = f2bf(dbuf[t]*iden);
    sf[2+9*CTXN+t] = f2bf(rbuf[t]*irden);
    float4 tf4 = *(const float4*)(ptf + (size_t)b*TPAST*NTF + (size_t)(176+t)*NTF);
    sf[2 + 10*CTXN + t] = f2bf(tf4.x);
    sf[2 + 11*CTXN + t] = f2bf(tf4.y);
    sf[2 + 12*CTXN + t] = f2bf(tf4.z);
    sf[2 + 13*CTXN + t] = f2bf(tf4.w);
  }
  for (int i=tid;i<NTF*PREDN;i+=256){
    int f = i/PREDN, t = i - f*PREDN;
    sf[2+14*CTXN + i] = f2bf(ftf[(size_t)b*PREDN*NTF + t*NTF + f]);
  }
  if (tid==0){ ls[b] = loc; ls[BATCH + b] = scale; }
}

/* ============ K2: base split-K GEMM (KC=8, 2 blocks/CU) || zgen (VALU) ====== */
__global__ __launch_bounds__(256) void bz_kernel(
    const char* __restrict__ wsb, float* __restrict__ partb)
{
  const int bid = blockIdx.x;
  const int tid = threadIdx.x;

  if (bid < NB_BASE){                       /* ---- base_partial (MFMA) ---- */
    const ush* sfb = (const ush*)(wsb + SFB_OFF);
    const ush* w1t = (const ush*)(wsb + W1T_OFF);
    const int w = tid>>6, l = tid&63;
    const int li = l&15, lk = l>>4;
    const int rb = (bid & 63)*16;
    const int kc = bid >> 6;                /* 0..7 */
    const int kbeg = kc*KCH;
    const int kend = min(SFKP, kbeg+KCH);

    f32x4 acc0 = {0.f,0.f,0.f,0.f}, acc1 = {0.f,0.f,0.f,0.f};
    const ush* ap  = sfb + (size_t)(rb + li)*SFKP + lk*8;
    const ush* b0p = w1t + (size_t)(w*32 + li)*SFKP + lk*8;
    const ush* b1p = b0p + (size_t)16*SFKP;

    #pragma unroll 4
    for (int kk0 = kbeg; kk0 < kend; kk0 += 32){
      bf16x8 a  = *(const bf16x8*)(ap  + kk0);
      bf16x8 b0 = *(const bf16x8*)(b0p + kk0);
      bf16x8 b1 = *(const bf16x8*)(b1p + kk0);
      acc0 = __builtin_amdgcn_mfma_f32_16x16x32_bf16(a, b0, acc0, 0, 0, 0);
      acc1 = __builtin_amdgcn_mfma_f32_16x16x32_bf16(a, b1, acc1, 0, 0, 0);
    }
    float* p = partb + ((size_t)kc*BATCH + rb)*HID;
    #pragma unroll
    for (int q=0;q<4;q++){
      p[(lk*4+q)*HID + w*32      + li] = acc0[q];
      p[(lk*4+q)*HID + w*32 + 16 + li] = acc1[q];
    }
    return;
  }

  /* ---- zgen: ILP-4 threefry (VALU; overlaps base's MFMA on same CUs) ---- */
  {
    float* zf = (float*)(wsb + ZF_OFF);
    const int g  = (bid - NB_BASE)*256 + tid;
    const int sb = g >> 3;
    const int t0 = (g & 7) * 4;
    const int s = sb >> 10, b = sb & 1023;
    const unsigned jb = (unsigned)(s*30720 + b*30 + t0);

    const unsigned k0=0u, k1=42u, k2 = k0^k1^0x1BD11BDAu;
    unsigned x0[4], x1[4];
    #pragma unroll
    for (int i=0;i<4;i++){ x0[i] = k0; x1[i] = (jb + (unsigned)i) + k1; }

    tf_rounds4(x0,x1,13,15,26,6);
    #pragma unroll
    for (int i=0;i<4;i++){ x0[i]+=k1; x1[i]+=k2+1u; }
    tf_rounds4(x0,x1,17,29,16,24);
    #pragma unroll
    for (int i=0;i<4;i++){ x0[i]+=k2; x1[i]+=k0+2u; }
    tf_rounds4(x0,x1,13,15,26,6);
    #pragma unroll
    for (int i=0;i<4;i++){ x0[i]+=k0; x1[i]+=k1+3u; }
    tf_rounds4(x0,x1,17,29,16,24);
    #pragma unroll
    for (int i=0;i<4;i++){ x0[i]+=k1; x1[i]+=k2+4u; }
    tf_rounds4(x0,x1,13,15,26,6);
    #pragma unroll
    for (int i=0;i<4;i++){ x0[i]+=k2; x1[i]+=k0+5u; }

    const float LO = -0.99999994f;
    float vout[4];
    #pragma unroll
    for (int i=0;i<4;i++){
      unsigned bits = x0[i]^x1[i];
      float f = __uint_as_float((bits>>9)|0x3f800000u) - 1.0f;
      float u = fmaxf(LO, f*2.0f + LO);
      vout[i] = 1.41421356f * erfinv_f32(u);
    }
    float4 v; v.x=vout[0]; v.y=vout[1]; v.z=vout[2]; v.w=vout[3];
    *(float4*)(zf + (size_t)sb*32 + t0) = v;
  }
}

/* ============ K3 mlp: grid (64,8)=512 blocks = 2/CU; u<4, s = sg+8*(wv+4u);
   72KB LDS staged once/block; KC=8 fused reduce; one barrier. (R16 form) ==== */
__global__ __launch_bounds__(256) void mlp_kernel(
    const char* __restrict__ wsb, const float* __restrict__ b1v,
    const float* __restrict__ b2v, const float* __restrict__ b3v,
    float* __restrict__ out)
{
  const int tid = threadIdx.x;
  const int wv = tid>>6, l = tid&63;
  const int li = l&15, lk = l>>4;
  const int r0 = blockIdx.x*16;
  const int sg = blockIdx.y;               /* 0..7 */

  const float* ls    = (const float*)(wsb + LS_OFF_B);
  const float* zf    = (const float*)(wsb + ZF_OFF);
  const float* partb = (const float*)(wsb + PART_OFF_B);
  const char*  wpkc  = wsb + WPK_OFF_B;

  __shared__ __attribute__((aligned(16))) ush  wlds[24576];  /* 48KB swizzled weights */
  __shared__ __attribute__((aligned(16))) float blds[2048];  /* 8KB base rows (reduced) */
  __shared__ __attribute__((aligned(16))) ush  hb4[4][2048]; /* wave-private h buf */
  char* hb = (char*)hb4[wv];
  char* wl = (char*)wlds;

  /* ---- stage weights (swizzle at write; linear global read) ---- */
  #pragma unroll
  for (int i=0;i<12;i++){
    int byte = (i*256 + tid)*16;
    int swz;
    if (byte < 8192){ int col = byte>>6; swz = byte ^ ((col&3)<<4); }
    else if (byte < 40960){ int X = byte - 8192; int col = X>>8; swz = 8192 + (X ^ ((col&7)<<4)); }
    else { int X = byte - 40960; int col = X>>8; swz = 40960 + (X ^ ((col&7)<<4)); }
    *(float4*)(wl + swz) = *(const float4*)(wpkc + byte);
  }
  /* ---- stage base rows with fused split-K reduce: blds = b1 + sum partb ---- */
  #pragma unroll
  for (int k=0;k<8;k++){
    int i = k*256 + tid;               /* 0..2047 = row*128 + h */
    float acc = b1v[i & 127];
    #pragma unroll
    for (int kc=0;kc<KC;kc++)
      acc += partb[(size_t)kc*BATCH*HID + (size_t)r0*HID + i];
    blds[i] = acc;
  }
  __syncthreads();

  /* ---- block-invariant registers ---- */
  float b2r[8];
  #pragma unroll
  for (int ct=0; ct<8; ct++) b2r[ct] = b2v[ct*16 + li];
  float b3r[2];
  #pragma unroll
  for (int ct3=0; ct3<2; ct3++){
    int col = ct3*16 + li;
    b3r[ct3] = (col < PREDN) ? b3v[col] : 0.f;
  }
  float loc4[4], scl4[4];
  #pragma unroll
  for (int q=0;q<4;q++){
    int gb = r0 + lk*4 + q;
    loc4[q] = ls[gb];
    scl4[q] = ls[BATCH + gb];
  }
  const int swzli  = (li&7)<<4;
  const int swzli3 = (li&3)<<4;

  #pragma unroll
  for (int u=0; u<4; u++){
    const int s = sg + 8*(wv + 4*u);   /* wave-uniform, DISTINCT per wave */
    if (s >= NSAMP) continue;

    /* early global loads: z A-frag source + epilogue z */
    const float* zrow = zf + ((size_t)(s*BATCH + r0 + li))*32 + lk*8;
    float4 za0 = *(const float4*)zrow;
    float4 za1 = *(const float4*)(zrow + 4);
    float zep[2][4];
    #pragma unroll
    for (int q=0;q<4;q++){
      const float* zr2 = zf + ((size_t)(s*BATCH + r0 + lk*4 + q))*32;
      zep[0][q] = zr2[li];
      zep[1][q] = zr2[16 + li];
    }

    /* acc init from base (LDS) */
    f32x4 acc[8];
    #pragma unroll
    for (int ct=0; ct<8; ct++){
      #pragma unroll
      for (int q=0;q<4;q++)
        acc[ct][q] = blds[(lk*4+q)*HID + ct*16 + li];
    }

    bf16x8 az;
    az[0]=(short)f2bf(za0.x); az[1]=(short)f2bf(za0.y);
    az[2]=(short)f2bf(za0.z); az[3]=(short)f2bf(za0.w);
    az[4]=(short)f2bf(za1.x); az[5]=(short)f2bf(za1.y);
    az[6]=(short)f2bf(za1.z); az[7]=(short)f2bf(za1.w);

    /* W1z stage (LDS swizzled reads) */
    #pragma unroll
    for (int ct=0; ct<8; ct++){
      bf16x8 w1f = *(const bf16x8*)(wl + (((ct*16+li)*64 + lk*16) ^ swzli3));
      acc[ct] = __builtin_amdgcn_mfma_f32_16x16x32_bf16(az, w1f, acc[ct], 0, 0, 0);
    }
    #pragma unroll
    for (int ct=0; ct<8; ct++){
      int col2 = (ct*16 + li)*2;
      #pragma unroll
      for (int q=0;q<4;q++){
        int r = lk*4 + q;
        *(ush*)(hb + r*256 + (col2 ^ ((r&7)<<4))) = f2bf(gelu_tanh(acc[ct][q]));
      }
    }

    /* W2 stage: K=128 */
    f32x4 acc2[8];
    #pragma unroll
    for (int ct=0; ct<8; ct++){
      acc2[ct][0]=b2r[ct]; acc2[ct][1]=b2r[ct]; acc2[ct][2]=b2r[ct]; acc2[ct][3]=b2r[ct];
    }
    #pragma unroll
    for (int ks=0; ks<4; ks++){
      bf16x8 a2 = *(const bf16x8*)(hb + li*256 + ((ks*64 + lk*16) ^ swzli));
      #pragma unroll
      for (int ct=0; ct<8; ct++){
        bf16x8 w2f = *(const bf16x8*)(wl + 8192 + (((ct*16+li)*256 + ks*64 + lk*16) ^ swzli));
        acc2[ct] = __builtin_amdgcn_mfma_f32_16x16x32_bf16(a2, w2f, acc2[ct], 0, 0, 0);
      }
    }
    #pragma unroll
    for (int ct=0; ct<8; ct++){
      int col2 = (ct*16 + li)*2;
      #pragma unroll
      for (int q=0;q<4;q++){
        int r = lk*4 + q;
        *(ush*)(hb + r*256 + (col2 ^ ((r&7)<<4))) = f2bf(gelu_tanh(acc2[ct][q]));
      }
    }

    /* W3 stage */
    f32x4 acc3[2];
    #pragma unroll
    for (int ct3=0; ct3<2; ct3++){
      acc3[ct3][0]=b3r[ct3]; acc3[ct3][1]=b3r[ct3];
      acc3[ct3][2]=b3r[ct3]; acc3[ct3][3]=b3r[ct3];
    }
    #pragma unroll
    for (int ks=0; ks<4; ks++){
      bf16x8 a3 = *(const bf16x8*)(hb + li*256 + ((ks*64 + lk*16) ^ swzli));
      #pragma unroll
      for (int ct3=0; ct3<2; ct3++){
        bf16x8 w3f = *(const bf16x8*)(wl + 40960 + (((ct3*16+li)*256 + ks*64 + lk*16) ^ swzli));
        acc3[ct3] = __builtin_amdgcn_mfma_f32_16x16x32_bf16(a3, w3f, acc3[ct3], 0, 0, 0);
      }
    }

    /* epilogue: (z - u)*scale + loc */
    #pragma unroll
    for (int ct3=0; ct3<2; ct3++){
      int col3 = ct3*16 + li;
      if (col3 < PREDN){
        #pragma unroll
        for (int q=0;q<4;q++){
          int gb = r0 + lk*4 + q;
          out[(size_t)gb*(NSAMP*PREDN) + s*PREDN + col3] =
              (zep[ct3][q] - acc3[ct3][q])*scl4[q] + loc4[q];
        }
      }
    }
  }
}

extern "C" void kernel_launch(void* const* d_in, const int* in_sizes, int n_in,
                              void* d_out, int out_size, void* d_ws, size_t ws_size,
                              hipStream_t stream) {
  (void)in_sizes; (void)n_in; (void)out_size; (void)ws_size;
  const float* pt  = (const float*)d_in[0];
  const float* ptf = (const float*)d_in[2];
  const float* ftf = (const float*)d_in[3];
  const float* W1  = (const float*)d_in[4];
  const float* b1  = (const float*)d_in[5];
  const float* W2  = (const float*)d_in[6];
  const float* b2  = (const float*)d_in[7];
  const float* W3  = (const float*)d_in[8];
  const float* b3  = (const float*)d_in[9];
  float* out = (float*)d_out;
  char* wsb  = (char*)d_ws;

  hipLaunchKernelGGL(prep_kernel, dim3(NB_PREP), dim3(256), 0, stream,
                     pt, ptf, ftf, W1, W2, W3, wsb);
  hipLaunchKernelGGL(bz_kernel, dim3(NB_BZ), dim3(256), 0, stream,
                     wsb, (float*)(wsb + PART_OFF_B));
  hipLaunchKernelGGL(mlp_kernel, dim3(64, 8), dim3(256), 0, stream,
                     wsb, b1, b2, b3, out);
}

// Round 19
// 51.615 us; speedup vs baseline: 1.1771x; 1.0264x over previous
//
#include <hip/hip_runtime.h>
#include <math.h>

#define CTXN 336
#define PREDN 30
#define NSAMP 100
#define BATCH 1024
#define TPAST 512
#define HID 128
#define NTF 4
#define SFK 4826          /* th(2) + 14*336 + 120 : maps to W1 rows 30..4855 */
#define SFKP 4832         /* padded to multiple of 32; pad region zeroed */
#define KC 8
#define KCH 608           /* 7 chunks of 608 + last 576; all %32==0 */

/* ---- ws layout in BYTES ---- */
#define SFB_OFF    0u                        /* ush  [1024][4832]   9,895,936 */
#define W1T_OFF    9895936u                  /* ush  [128][4832]    1,236,992 */
#define LS_OFF_B   11132928u                 /* f32  loc[1024], scale[1024]   */
#define ZBF_OFF    11141120u                 /* ush  [100][1024][32] 6,553,600 */
#define PART_OFF_B 30801920u                 /* f32  [8][1024][128]  4,194,304 */
#define WPK_OFF_B  39714816u                 /* ush  24576 packs (49152 B)    */

/* K1 grid: feat FIRST (longest blocks), then w1t, wpk */
#define NB_FEAT 1024
#define NB_W1T  151
#define NB_WPK  16
#define NB_PREP (NB_FEAT+NB_W1T+NB_WPK)

/* K2 grid: base (512 = 2/CU, longest) first, then zgen (3200) */
#define NB_BASE 512
#define NB_ZGEN 3200
#define NB_BZ   (NB_BASE+NB_ZGEN)

typedef unsigned short ush;
typedef __attribute__((ext_vector_type(8))) short bf16x8;
typedef __attribute__((ext_vector_type(4))) float f32x4;

__device__ inline unsigned rotl32(unsigned x, unsigned d){ return (x<<d)|(x>>(32u-d)); }

/* XLA ErfInv32 (Giles); log1p via hw v_log on (1-x)(1+x), hw sqrt */
__device__ inline float erfinv_f32(float x){
  float t1 = (1.0f - x)*(1.0f + x);
  float w = -0.69314718056f * __builtin_amdgcn_logf(t1);
  float p;
  if (w < 5.0f) {
    w -= 2.5f;
    p = 2.81022636e-08f;
    p = fmaf(p, w, 3.43273939e-07f);
    p = fmaf(p, w, -3.5233877e-06f);
    p = fmaf(p, w, -4.39150654e-06f);
    p = fmaf(p, w, 0.00021858087f);
    p = fmaf(p, w, -0.00125372503f);
    p = fmaf(p, w, -0.00417768164f);
    p = fmaf(p, w, 0.246640727f);
    p = fmaf(p, w, 1.50140941f);
  } else {
    w = __builtin_amdgcn_sqrtf(w) - 3.0f;
    p = -0.000200214257f;
    p = fmaf(p, w, 0.000100950558f);
    p = fmaf(p, w, 0.00134934322f);
    p = fmaf(p, w, -0.00367342844f);
    p = fmaf(p, w, 0.00573950773f);
    p = fmaf(p, w, -0.0076224613f);
    p = fmaf(p, w, 0.00943887047f);
    p = fmaf(p, w, 1.00167406f);
    p = fmaf(p, w, 2.83297682f);
  }
  return p*x;
}

/* gelu(tanh form): 8 VALU via hw exp2/rcp */
__device__ inline float gelu_tanh(float x){
  float x2 = x*x;
  float q  = fmaf(0.044715f*x2, x, x);
  float e  = __builtin_amdgcn_exp2f(2.302114202f * q);
  float r  = __builtin_amdgcn_rcpf(e + 1.0f);
  return fmaf(-x, r, x);
}

/* f32 -> bf16 RNE (prep/zgen: feeds many consumers, keep unbiased) */
__device__ inline ush f2bf(float f){
  unsigned u = __float_as_uint(f);
  unsigned r = (u + 0x7FFFu + ((u>>16)&1u)) >> 16;
  return (ush)r;
}
/* f32 -> bf16 truncate (mlp hot path: 1 op; bias ~2^-9 toward 0, harmless) */
__device__ inline ush f2bf_t(float f){
  return (ush)(__float_as_uint(f) >> 16);
}
/* bf16 -> f32 */
__device__ inline float bf2f(ush v){
  return __uint_as_float(((unsigned)v) << 16);
}

/* order-preserving float<->uint map (total order; exact) */
__device__ inline unsigned ordf(float f){
  unsigned u = __float_as_uint(f);
  return (u & 0x80000000u) ? ~u : (u | 0x80000000u);
}
__device__ inline float unordf(unsigned ou){
  unsigned u = (ou & 0x80000000u) ? (ou & 0x7FFFFFFFu) : ~ou;
  return __uint_as_float(u);
}

__device__ inline float blockReduceSum256(float v, volatile float* red){
  for (int o=32;o>0;o>>=1) v += __shfl_down(v, o, 64);
  int w = threadIdx.x>>6, lane = threadIdx.x&63;
  __syncthreads();
  if (lane==0) red[w]=v;
  __syncthreads();
  return red[0]+red[1]+red[2]+red[3];
}

__device__ inline unsigned blockReduceMin256(unsigned v, volatile unsigned* redu){
  for (int o=32;o>0;o>>=1){ unsigned t = __shfl_down(v, o, 64); v = (t<v)?t:v; }
  int w = threadIdx.x>>6, lane = threadIdx.x&63;
  __syncthreads();
  if (lane==0) redu[w]=v;
  __syncthreads();
  unsigned a = redu[0], b = redu[1], c = redu[2], d = redu[3];
  unsigned ab = (a<b)?a:b, cd = (c<d)?c:d;
  return (ab<cd)?ab:cd;
}

/* 4-wide ILP threefry rounds */
__device__ inline void tf_rounds4(unsigned (&x0)[4], unsigned (&x1)[4],
                                  int r0, int r1, int r2, int r3){
  #pragma unroll
  for (int i=0;i<4;i++){ x0[i]+=x1[i]; x1[i]=rotl32(x1[i],r0); x1[i]^=x0[i]; }
  #pragma unroll
  for (int i=0;i<4;i++){ x0[i]+=x1[i]; x1[i]=rotl32(x1[i],r1); x1[i]^=x0[i]; }
  #pragma unroll
  for (int i=0;i<4;i++){ x0[i]+=x1[i]; x1[i]=rotl32(x1[i],r2); x1[i]^=x0[i]; }
  #pragma unroll
  for (int i=0;i<4;i++){ x0[i]+=x1[i]; x1[i]=rotl32(x1[i],r3); x1[i]^=x0[i]; }
}

/* ============ K1 prep: feat | W1 transpose | small packs ============ */
__global__ __launch_bounds__(256) void prep_kernel(
    const float* __restrict__ pt, const float* __restrict__ ptf,
    const float* __restrict__ ftf, const float* __restrict__ W1,
    const float* __restrict__ W2, const float* __restrict__ W3,
    char* __restrict__ wsb)
{
  __shared__ float seg[343];
  __shared__ __attribute__((aligned(16))) float segA[CTXN];
  __shared__ float dbuf[CTXN];
  __shared__ float rbuf[CTXN];
  __shared__ float red[4];
  __shared__ unsigned redu[4];
  __shared__ int bins[16];
  const int bid = blockIdx.x;
  const int tid = threadIdx.x;

  if (bid >= NB_FEAT){
    const int b2id = bid - NB_FEAT;
    if (b2id < NB_W1T){                     /* ---- W1[30:] -> col-major bf16 ---- */
      ush* w1t = (ush*)(wsb + W1T_OFF);
      const int k0 = b2id*32;
      const int col = tid >> 1;
      const int kh  = (tid & 1)*16;
      ush v[16];
      #pragma unroll
      for (int j=0;j<16;j++){
        int k = k0 + kh + j;
        v[j] = (k < SFK) ? f2bf(W1[(size_t)(30+k)*HID + col]) : (ush)0;
      }
      ush* dst = w1t + (size_t)col*SFKP + k0 + kh;
      *(uint4*)dst       = *(const uint4*)&v[0];
      *(uint4*)(dst + 8) = *(const uint4*)&v[8];
      return;
    }
    {                                       /* ---- small packs (w1z/w2/w3) ---- */
      ush* wb = (ush*)(wsb + WPK_OFF_B);
      int t2 = (b2id - NB_W1T)*256 + tid;
      { int col = t2>>5, k = t2&31;
        wb[t2] = (k<30) ? f2bf(W1[(size_t)k*HID + col]) : (ush)0; }
      #pragma unroll
      for (int j=0;j<4;j++){
        int i = j*4096 + t2;
        int col = i>>7, k = i&127;
        wb[4096 + i] = f2bf(W2[(size_t)k*HID + col]);
      }
      { int col = t2>>7, k = t2&127;
        wb[20480 + t2] = (col<30) ? f2bf(W3[(size_t)k*PREDN + col]) : (ush)0; }
      return;
    }
  }

  /* ---- features (bid 0..1023, longest-first) ---- */
  const int b = bid;
  for (int i = tid; i < 343; i += 256) seg[i] = pt[(size_t)b*TPAST + 169 + i];
  __syncthreads();
  for (int i = tid; i < CTXN; i += 256) segA[i] = seg[7+i];
  __syncthreads();

  /* -------- median via exact radix-select (orderable-uint nibbles) -------- */
  const unsigned oe0 = ordf(segA[tid]);
  const bool has1 = (tid < CTXN - 256);
  const unsigned oe1 = has1 ? ordf(segA[256 + tid]) : 0u;

  unsigned pfx = 0u; int kk = 167;          /* find 167th smallest (0-indexed) */
  #pragma unroll
  for (int shift = 28; shift >= 0; shift -= 4){
    __syncthreads();
    if (tid < 16) bins[tid] = 0;
    __syncthreads();
    const unsigned hi_mask = (shift==28) ? 0u : (0xFFFFFFFFu << (shift+4));
    if (((oe0 ^ pfx) & hi_mask) == 0) atomicAdd(&bins[(oe0>>shift)&15], 1);
    if (has1 && (((oe1 ^ pfx) & hi_mask) == 0)) atomicAdd(&bins[(oe1>>shift)&15], 1);
    __syncthreads();
    int cum = 0, sel = 15;                  /* all threads scan redundantly */
    #pragma unroll
    for (int bb = 0; bb < 16; bb++){
      int c = bins[bb];
      if (kk < cum + c){ sel = bb; break; }
      cum += c;
    }
    kk -= cum;
    pfx |= ((unsigned)sel) << shift;
  }
  const float v167 = unordf(pfx);

  /* rank 168: duplicates -> same; else min over { x > v167 } */
  float cle = ((oe0 <= pfx) ? 1.f : 0.f) + ((has1 && oe1 <= pfx) ? 1.f : 0.f);
  cle = blockReduceSum256(cle, red);
  unsigned mg = (oe0 > pfx) ? oe0 : 0xFFFFFFFFu;
  if (has1 && oe1 > pfx && oe1 < mg) mg = oe1;
  mg = blockReduceMin256(mg, redu);
  const float v168 = (cle >= 168.5f) ? v167 : unordf(mg);
  const float loc = 0.5f*(v167 + v168);

  float part = 0.f;
  for (int t=tid;t<CTXN;t+=256) part += fabsf(segA[t]-loc);
  part = blockReduceSum256(part, red);
  float scale = fmaxf(part/(float)CTXN, 1e-6f);

  float pd = 0.f;
  for (int t=tid;t<CTXN;t+=256){
    float d = (t==0)?0.f:(seg[7+t]-seg[6+t]);
    dbuf[t]=d; pd += fabsf(d);
  }
  pd = blockReduceSum256(pd, red);
  float dden = fmaxf(pd/(float)CTXN, 1e-6f);

  float pr = 0.f;
  for (int t=tid;t<CTXN;t+=256){
    int a = t-4; if (a<0) a=0;
    int n = t+1-a;
    float s=0.f, s2s=0.f;
    for (int jj=a;jj<=t;jj++){ float v=seg[7+jj]; s+=v; s2s+=v*v; }
    float fn = (float)n;
    float var = (s2s - s*s/fn) / fmaxf(fn-1.f, 1.f);
    float r = (t>=2)? sqrtf(fmaxf(var,1e-12f)) : 0.f;
    rbuf[t]=r; pr += r;
  }
  pr = blockReduceSum256(pr, red);
  float rden = fmaxf(pr/(float)CTXN, 1e-6f);
  __syncthreads();

  ush* sf = (ush*)(wsb + SFB_OFF) + (size_t)b*SFKP;
  float* ls = (float*)(wsb + LS_OFF_B);
  if (tid<2) sf[tid] = (ush)0x3F80;
  if (tid<SFKP-SFK) sf[SFK+tid] = 0;
  float iscale = 1.0f/scale, iden = 1.0f/dden, irden = 1.0f/rden;
  for (int t=tid;t<CTXN;t+=256){
    #pragma unroll
    for (int c=0;c<8;c++)
      sf[2 + c*CTXN + t] = f2bf((seg[7 - c + t] - loc)*iscale);
    sf[2+8*CTXN+t] = f2bf(dbuf[t]*iden);
    sf[2+9*CTXN+t] = f2bf(rbuf[t]*irden);
    float4 tf4 = *(const float4*)(ptf + (size_t)b*TPAST*NTF + (size_t)(176+t)*NTF);
    sf[2 + 10*CTXN + t] = f2bf(tf4.x);
    sf[2 + 11*CTXN + t] = f2bf(tf4.y);
    sf[2 + 12*CTXN + t] = f2bf(tf4.z);
    sf[2 + 13*CTXN + t] = f2bf(tf4.w);
  }
  for (int i=tid;i<NTF*PREDN;i+=256){
    int f = i/PREDN, t = i - f*PREDN;
    sf[2+14*CTXN + i] = f2bf(ftf[(size_t)b*PREDN*NTF + t*NTF + f]);
  }
  if (tid==0){ ls[b] = loc; ls[BATCH + b] = scale; }
}

/* ============ K2: base split-K GEMM (KC=8, 2 blocks/CU) || zgen (VALU) ====== */
__global__ __launch_bounds__(256) void bz_kernel(
    const char* __restrict__ wsb, float* __restrict__ partb)
{
  const int bid = blockIdx.x;
  const int tid = threadIdx.x;

  if (bid < NB_BASE){                       /* ---- base_partial (MFMA) ---- */
    const ush* sfb = (const ush*)(wsb + SFB_OFF);
    const ush* w1t = (const ush*)(wsb + W1T_OFF);
    const int w = tid>>6, l = tid&63;
    const int li = l&15, lk = l>>4;
    const int rb = (bid & 63)*16;
    const int kc = bid >> 6;                /* 0..7 */
    const int kbeg = kc*KCH;
    const int kend = min(SFKP, kbeg+KCH);

    f32x4 acc0 = {0.f,0.f,0.f,0.f}, acc1 = {0.f,0.f,0.f,0.f};
    const ush* ap  = sfb + (size_t)(rb + li)*SFKP + lk*8;
    const ush* b0p = w1t + (size_t)(w*32 + li)*SFKP + lk*8;
    const ush* b1p = b0p + (size_t)16*SFKP;

    #pragma unroll 4
    for (int kk0 = kbeg; kk0 < kend; kk0 += 32){
      bf16x8 a  = *(const bf16x8*)(ap  + kk0);
      bf16x8 b0 = *(const bf16x8*)(b0p + kk0);
      bf16x8 b1 = *(const bf16x8*)(b1p + kk0);
      acc0 = __builtin_amdgcn_mfma_f32_16x16x32_bf16(a, b0, acc0, 0, 0, 0);
      acc1 = __builtin_amdgcn_mfma_f32_16x16x32_bf16(a, b1, acc1, 0, 0, 0);
    }
    float* p = partb + ((size_t)kc*BATCH + rb)*HID;
    #pragma unroll
    for (int q=0;q<4;q++){
      p[(lk*4+q)*HID + w*32      + li] = acc0[q];
      p[(lk*4+q)*HID + w*32 + 16 + li] = acc1[q];
    }
    return;
  }

  /* ---- zgen: ILP-4 threefry -> bf16 z (VALU; overlaps base's MFMA) ---- */
  {
    ush* zb = (ush*)(wsb + ZBF_OFF);
    const int g  = (bid - NB_BASE)*256 + tid;
    const int sb = g >> 3;
    const int t0 = (g & 7) * 4;
    const int s = sb >> 10, b = sb & 1023;
    const unsigned jb = (unsigned)(s*30720 + b*30 + t0);

    const unsigned k0=0u, k1=42u, k2 = k0^k1^0x1BD11BDAu;
    unsigned x0[4], x1[4];
    #pragma unroll
    for (int i=0;i<4;i++){ x0[i] = k0; x1[i] = (jb + (unsigned)i) + k1; }

    tf_rounds4(x0,x1,13,15,26,6);
    #pragma unroll
    for (int i=0;i<4;i++){ x0[i]+=k1; x1[i]+=k2+1u; }
    tf_rounds4(x0,x1,17,29,16,24);
    #pragma unroll
    for (int i=0;i<4;i++){ x0[i]+=k2; x1[i]+=k0+2u; }
    tf_rounds4(x0,x1,13,15,26,6);
    #pragma unroll
    for (int i=0;i<4;i++){ x0[i]+=k0; x1[i]+=k1+3u; }
    tf_rounds4(x0,x1,17,29,16,24);
    #pragma unroll
    for (int i=0;i<4;i++){ x0[i]+=k1; x1[i]+=k2+4u; }
    tf_rounds4(x0,x1,13,15,26,6);
    #pragma unroll
    for (int i=0;i<4;i++){ x0[i]+=k2; x1[i]+=k0+5u; }

    const float LO = -0.99999994f;
    float vout[4];
    #pragma unroll
    for (int i=0;i<4;i++){
      unsigned bits = x0[i]^x1[i];
      float f = __uint_as_float((bits>>9)|0x3f800000u) - 1.0f;
      float u = fmaxf(LO, f*2.0f + LO);
      vout[i] = (t0 + i < 30) ? 1.41421356f * erfinv_f32(u) : 0.f;
    }
    uint2 pv;
    pv.x = (unsigned)f2bf(vout[0]) | ((unsigned)f2bf(vout[1]) << 16);
    pv.y = (unsigned)f2bf(vout[2]) | ((unsigned)f2bf(vout[3]) << 16);
    *(uint2*)(zb + (size_t)sb*32 + t0) = pv;
  }
}

/* ============ K3 mlp: grid (64,8)=512 blocks = 2/CU; u<4, s = sg+8*(wv+4u);
   72KB LDS staged once/block; KC=8 fused reduce; bf16 z direct A-frag;
   truncating f2bf_t on h writes. =========================================== */
__global__ __launch_bounds__(256) void mlp_kernel(
    const char* __restrict__ wsb, const float* __restrict__ b1v,
    const float* __restrict__ b2v, const float* __restrict__ b3v,
    float* __restrict__ out)
{
  const int tid = threadIdx.x;
  const int wv = tid>>6, l = tid&63;
  const int li = l&15, lk = l>>4;
  const int r0 = blockIdx.x*16;
  const int sg = blockIdx.y;               /* 0..7 */

  const float* ls    = (const float*)(wsb + LS_OFF_B);
  const ush*   zbf   = (const ush*)(wsb + ZBF_OFF);
  const float* partb = (const float*)(wsb + PART_OFF_B);
  const char*  wpkc  = wsb + WPK_OFF_B;

  __shared__ __attribute__((aligned(16))) ush  wlds[24576];  /* 48KB swizzled weights */
  __shared__ __attribute__((aligned(16))) float blds[2048];  /* 8KB base rows (reduced) */
  __shared__ __attribute__((aligned(16))) ush  hb4[4][2048]; /* wave-private h buf */
  char* hb = (char*)hb4[wv];
  char* wl = (char*)wlds;

  /* ---- stage weights (swizzle at write; linear global read) ---- */
  #pragma unroll
  for (int i=0;i<12;i++){
    int byte = (i*256 + tid)*16;
    int swz;
    if (byte < 8192){ int col = byte>>6; swz = byte ^ ((col&3)<<4); }
    else if (byte < 40960){ int X = byte - 8192; int col = X>>8; swz = 8192 + (X ^ ((col&7)<<4)); }
    else { int X = byte - 40960; int col = X>>8; swz = 40960 + (X ^ ((col&7)<<4)); }
    *(float4*)(wl + swz) = *(const float4*)(wpkc + byte);
  }
  /* ---- stage base rows with fused split-K reduce: blds = b1 + sum partb ---- */
  #pragma unroll
  for (int k=0;k<8;k++){
    int i = k*256 + tid;               /* 0..2047 = row*128 + h */
    float acc = b1v[i & 127];
    #pragma unroll
    for (int kc=0;kc<KC;kc++)
      acc += partb[(size_t)kc*BATCH*HID + (size_t)r0*HID + i];
    blds[i] = acc;
  }
  __syncthreads();

  /* ---- block-invariant registers ---- */
  float b2r[8];
  #pragma unroll
  for (int ct=0; ct<8; ct++) b2r[ct] = b2v[ct*16 + li];
  float b3r[2];
  #pragma unroll
  for (int ct3=0; ct3<2; ct3++){
    int col = ct3*16 + li;
    b3r[ct3] = (col < PREDN) ? b3v[col] : 0.f;
  }
  float loc4[4], scl4[4];
  #pragma unroll
  for (int q=0;q<4;q++){
    int gb = r0 + lk*4 + q;
    loc4[q] = ls[gb];
    scl4[q] = ls[BATCH + gb];
  }
  const int swzli  = (li&7)<<4;
  const int swzli3 = (li&3)<<4;

  #pragma unroll
  for (int u=0; u<4; u++){
    const int s = sg + 8*(wv + 4*u);   /* wave-uniform, DISTINCT per wave */
    if (s >= NSAMP) continue;

    /* early global loads: z A-frag (bf16 direct) + epilogue z (bf16) */
    bf16x8 az = *(const bf16x8*)&zbf[((size_t)(s*BATCH + r0 + li))*32 + lk*8];
    float zep[2][4];
    #pragma unroll
    for (int q=0;q<4;q++){
      const ush* zr2 = zbf + ((size_t)(s*BATCH + r0 + lk*4 + q))*32;
      zep[0][q] = bf2f(zr2[li]);
      zep[1][q] = bf2f(zr2[16 + li]);
    }

    /* acc init from base (LDS) */
    f32x4 acc[8];
    #pragma unroll
    for (int ct=0; ct<8; ct++){
      #pragma unroll
      for (int q=0;q<4;q++)
        acc[ct][q] = blds[(lk*4+q)*HID + ct*16 + li];
    }

    /* W1z stage (LDS swizzled reads) */
    #pragma unroll
    for (int ct=0; ct<8; ct++){
      bf16x8 w1f = *(const bf16x8*)(wl + (((ct*16+li)*64 + lk*16) ^ swzli3));
      acc[ct] = __builtin_amdgcn_mfma_f32_16x16x32_bf16(az, w1f, acc[ct], 0, 0, 0);
    }
    #pragma unroll
    for (int ct=0; ct<8; ct++){
      int col2 = (ct*16 + li)*2;
      #pragma unroll
      for (int q=0;q<4;q++){
        int r = lk*4 + q;
        *(ush*)(hb + r*256 + (col2 ^ ((r&7)<<4))) = f2bf_t(gelu_tanh(acc[ct][q]));
      }
    }

    /* W2 stage: K=128 */
    f32x4 acc2[8];
    #pragma unroll
    for (int ct=0; ct<8; ct++){
      acc2[ct][0]=b2r[ct]; acc2[ct][1]=b2r[ct]; acc2[ct][2]=b2r[ct]; acc2[ct][3]=b2r[ct];
    }
    #pragma unroll
    for (int ks=0; ks<4; ks++){
      bf16x8 a2 = *(const bf16x8*)(hb + li*256 + ((ks*64 + lk*16) ^ swzli));
      #pragma unroll
      for (int ct=0; ct<8; ct++){
        bf16x8 w2f = *(const bf16x8*)(wl + 8192 + (((ct*16+li)*256 + ks*64 + lk*16) ^ swzli));
        acc2[ct] = __builtin_amdgcn_mfma_f32_16x16x32_bf16(a2, w2f, acc2[ct], 0, 0, 0);
      }
    }
    #pragma unroll
    for (int ct=0; ct<8; ct++){
      int col2 = (ct*16 + li)*2;
      #pragma unroll
      for (int q=0;q<4;q++){
        int r = lk*4 + q;
        *(ush*)(hb + r*256 + (col2 ^ ((r&7)<<4))) = f2bf_t(gelu_tanh(acc2[ct][q]));
      }
    }

    /* W3 stage */
    f32x4 acc3[2];
    #pragma unroll
    for (int ct3=0; ct3<2; ct3++){
      acc3[ct3][0]=b3r[ct3]; acc3[ct3][1]=b3r[ct3];
      acc3[ct3][2]=b3r[ct3]; acc3[ct3][3]=b3r[ct3];
    }
    #pragma unroll
    for (int ks=0; ks<4; ks++){
      bf16x8 a3 = *(const bf16x8*)(hb + li*256 + ((ks*64 + lk*16) ^ swzli));
      #pragma unroll
      for (int ct3=0; ct3<2; ct3++){
        bf16x8 w3f = *(const bf16x8*)(wl + 40960 + (((ct3*16+li)*256 + ks*64 + lk*16) ^ swzli));
        acc3[ct3] = __builtin_amdgcn_mfma_f32_16x16x32_bf16(a3, w3f, acc3[ct3], 0, 0, 0);
      }
    }

    /* epilogue: (z - u)*scale + loc */
    #pragma unroll
    for (int ct3=0; ct3<2; ct3++){
      int col3 = ct3*16 + li;
      if (col3 < PREDN){
        #pragma unroll
        for (int q=0;q<4;q++){
          int gb = r0 + lk*4 + q;
          out[(size_t)gb*(NSAMP*PREDN) + s*PREDN + col3] =
              (zep[ct3][q] - acc3[ct3][q])*scl4[q] + loc4[q];
        }
      }
    }
  }
}

extern "C" void kernel_launch(void* const* d_in, const int* in_sizes, int n_in,
                              void* d_out, int out_size, void* d_ws, size_t ws_size,
                              hipStream_t stream) {
  (void)in_sizes; (void)n_in; (void)out_size; (void)ws_size;
  const float* pt  = (const float*)d_in[0];
  const float* ptf = (const float*)d_in[2];
  const float* ftf = (const float*)d_in[3];
  const float* W1  = (const float*)d_in[4];
  const float* b1  = (const float*)d_in[5];
  const float* W2  = (const float*)d_in[6];
  const float* b2  = (const float*)d_in[7];
  const float* W3  = (const float*)d_in[8];
  const float* b3  = (const float*)d_in[9];
  float* out = (float*)d_out;
  char* wsb  = (char*)d_ws;

  hipLaunchKernelGGL(prep_kernel, dim3(NB_PREP), dim3(256), 0, stream,
                     pt, ptf, ftf, W1, W2, W3, wsb);
  hipLaunchKernelGGL(bz_kernel, dim3(NB_BZ), dim3(256), 0, stream,
                     wsb, (float*)(wsb + PART_OFF_B));
  hipLaunchKernelGGL(mlp_kernel, dim3(64, 8), dim3(256), 0, stream,
                     wsb, b1, b2, b3, out);
}